// Round 8
// baseline (392.593 us; speedup 1.0000x reference)
//
#include <hip/hip_runtime.h>
#include <hip/hip_bf16.h>

typedef __bf16 bf16x8 __attribute__((ext_vector_type(8)));
typedef __bf16 bf16x4 __attribute__((ext_vector_type(4)));
typedef float f32x4 __attribute__((ext_vector_type(4)));
typedef float f32x3 __attribute__((ext_vector_type(3)));
typedef unsigned int u32x3 __attribute__((ext_vector_type(3)));
typedef unsigned short u16;
typedef unsigned int u32;

// Problem constants
#define B_   4
#define C_   128
#define K_   13
#define A_   12
#define P_   1024
#define D_   128
#define R_   12
#define NB   1024          // n per batch (b-local)
// K' = 5 groups * 128c * 12a = 7680 = 80 tiles of 96; per split-group: 16 tiles

#define AS1 __attribute__((address_space(1)))
#define AS3 __attribute__((address_space(3)))

__device__ __forceinline__ u16 f2bf(float f) {
    u32 u = __builtin_bit_cast(u32, f);
    u32 r = (u + 0x7FFFu + ((u >> 16) & 1u)) >> 16;
    return (u16)r;
}
__device__ __forceinline__ float bf2f(u16 v) {
    u32 u = (u32)v << 16;
    return __builtin_bit_cast(float, u);
}
__device__ __forceinline__ u32 pack2(float lo, float hi) {
    return (u32)f2bf(lo) | ((u32)f2bf(hi) << 16);
}

__device__ __forceinline__ void barrier_() {
    asm volatile("" ::: "memory");
    __builtin_amdgcn_s_barrier();
    asm volatile("" ::: "memory");
}
__device__ __forceinline__ void lgkm0_() {
    asm volatile("s_waitcnt lgkmcnt(0)" ::: "memory");
    __builtin_amdgcn_sched_barrier(0);
}
#define VMW(n) asm volatile("s_waitcnt vmcnt(" #n ")" ::: "memory")

// ---------------------------------------------------------------------------
// poolk_b: x_b[c,k,p,a] f32 -> pool[j][c][p][a] bf16 (ONE batch), j in [0,26):
//   j=0..12 raw k-slices; j=13 T = sum_{k<12}; j=14+r N_r = shell1 sum.
// Grid (128 c, 4 p-quarters), 512 thr: thread -> (p = pp*256 + t>>1, a-half).
// ---------------------------------------------------------------------------
__global__ __launch_bounds__(512) void poolk_b(const float* __restrict__ xb_,
                                               const int* __restrict__ kidx3,
                                               u16* __restrict__ pool) {
    const int c  = blockIdx.x;
    const int pp = blockIdx.y;
    const int t  = threadIdx.x;
    const int ah = t & 1, aoff = ah * 6;

    u32 m1[12];
#pragma unroll
    for (int k = 0; k < 12; ++k) {
        u32 m = 0;
#pragma unroll
        for (int r = 0; r < 12; ++r)
            m |= (kidx3[k * 144 + r] == 1 ? 1u : 0u) << r;
        m1[k] = m;
    }

    const float* xb = xb_ + (size_t)c * (K_ * (size_t)P_ * A_);
    const size_t cslab   = (size_t)c * NB * 12;
    const size_t jstride = (size_t)C_ * NB * 12;

    int p = pp * 256 + (t >> 1);
    size_t obase = cslab + (size_t)p * 12 + aoff;
    float T[6] = {0.f, 0.f, 0.f, 0.f, 0.f, 0.f};
    float N[12][6];
#pragma unroll
    for (int r = 0; r < 12; ++r)
#pragma unroll
        for (int j = 0; j < 6; ++j) N[r][j] = 0.f;

#pragma unroll
    for (int k = 0; k < 13; ++k) {
        const float* s = xb + (size_t)k * (P_ * A_) + p * 12 + aoff;
        f32x3 v0 = *(const f32x3*)s;
        f32x3 v1 = *(const f32x3*)(s + 3);
        float v[6] = {v0.x, v0.y, v0.z, v1.x, v1.y, v1.z};
        u32x3 o;
        o.x = pack2(v[0], v[1]); o.y = pack2(v[2], v[3]); o.z = pack2(v[4], v[5]);
        *(u32x3*)(pool + (size_t)k * jstride + obase) = o;
        if (k < 12) {
#pragma unroll
            for (int j = 0; j < 6; ++j) T[j] += v[j];
            u32 m = m1[k];
#pragma unroll
            for (int r = 0; r < 12; ++r) {
                if (m & (1u << r)) {
#pragma unroll
                    for (int j = 0; j < 6; ++j) N[r][j] += v[j];
                }
            }
        }
    }
    {
        u32x3 o;
        o.x = pack2(T[0], T[1]); o.y = pack2(T[2], T[3]); o.z = pack2(T[4], T[5]);
        *(u32x3*)(pool + (size_t)13 * jstride + obase) = o;
    }
#pragma unroll
    for (int r = 0; r < 12; ++r) {
        u32x3 o;
        o.x = pack2(N[r][0], N[r][1]); o.y = pack2(N[r][2], N[r][3]); o.z = pack2(N[r][4], N[r][5]);
        *(u32x3*)(pool + (size_t)(14 + r) * jstride + obase) = o;
    }
}

// ---------------------------------------------------------------------------
// abuild: tile-major panels Ab[r][tile][d][96] bf16, XOR swizzle baked in
// (phys chunk chp holds logical chunk chp ^ ((d>>1)&3) within each ks-group).
// Values: g0:(W0-W2) g1:(W1-W2) g2:W2 g3:(W3-W2) g4:W4 at aa = aidx[a,r],
// logical col q = g*1536 + c*12 + a; tile = q/96.
// ---------------------------------------------------------------------------
__global__ __launch_bounds__(256) void abuild(const float* __restrict__ W,
                                              const int* __restrict__ aidx3,
                                              u16* __restrict__ Ab) {
    int gidx = blockIdx.x * 256 + threadIdx.x;   // 12*128*960 = 1,474,560
    int r   = gidx / (128 * 960);
    int rem = gidx - r * (128 * 960);
    int d   = rem / 960;
    int p8  = rem - d * 960;
    int phys = p8 * 8;
    int tile = phys / 96;
    int w96  = phys - tile * 96;
    int ks   = w96 >> 5;
    int chp  = (w96 >> 3) & 3;
    int ch   = chp ^ ((d >> 1) & 3);
    int qbase = tile * 96 + ks * 32 + ch * 8;
    u16 o[8];
#pragma unroll
    for (int e = 0; e < 8; ++e) {
        int q  = qbase + e;
        int g  = q / 1536;
        int qq = q - g * 1536;
        int c  = qq / 12;
        int a  = qq - c * 12;
        int aa = aidx3[a * 12 + r];
        const float* wb = W + ((size_t)(d * C_ + c) * 5) * 12 + aa;
        float val;
        if (g == 2)      val = wb[2 * 12];
        else if (g == 4) val = wb[4 * 12];
        else             val = wb[g * 12] - wb[2 * 12];
        o[e] = f2bf(val);
    }
    uint4 v;
    v.x = (u32)o[0] | ((u32)o[1] << 16);
    v.y = (u32)o[2] | ((u32)o[3] << 16);
    v.z = (u32)o[4] | ((u32)o[5] << 16);
    v.w = (u32)o[6] | ((u32)o[7] << 16);
    *(uint4*)(Ab + (((size_t)(r * 80 + tile) * 128 + d) * 96 + w96)) = v;
}

// ---------------------------------------------------------------------------
// gemmSb: per (r, nt, sp): C[d][n] += over K-chunk of group sp (16 tiles).
// 240 blocks = 4nt x 12r x 5sp, single residency round. sp == shell-group:
// j = {k0r, 14+r, 13, k3r, 12}[sp]. BM=128, BN=256, BK=96, 8 waves (2Mx4N),
// dbuf LDS, 16B global_load_lds only, counted vmcnt(9).
// Pool is b-local (just written -> L3-resident). Writes bf16 slab [sp].
// ---------------------------------------------------------------------------
__global__ __launch_bounds__(512) void gemmSb(const u16* __restrict__ Ab,
                                              const u16* __restrict__ pool,
                                              const int* __restrict__ kidx3,
                                              u16* __restrict__ Ctb) {
    __shared__ __align__(16) u16 sA[2][128 * 96];
    __shared__ __align__(16) u16 sB[2][8 * 256 * 12];

    int bx = blockIdx.x;                 // 240
    int r  = bx % 12;
    int nt = (bx / 12) & 3;
    int sp = bx / 48;                    // 0..4 == group
    int n0 = nt * 256;

    int k0r = 0, k3r = 0;
    for (int k = 0; k < 13; ++k) {
        int kv = kidx3[k * 144 + r];
        if (kv == 0) k0r = k;
        if (kv == 3) k3r = k;
    }
    int j = (sp == 0) ? k0r : (sp == 1) ? (14 + r) : (sp == 2) ? 13
          : (sp == 3) ? k3r : 12;

    int lane = threadIdx.x & 63;
    int w    = threadIdx.x >> 6;
    int wm   = w >> 2, wn = w & 3;
    int lq   = lane & 15;

    auto stageA = [&](int buf, int u) {       // tile = sp*16 + u
        const char* src = (const char*)(Ab + (size_t)(r * 80 + sp * 16 + u) * (128 * 96))
                        + w * 3072 + lane * 16;
#pragma unroll
        for (int i = 0; i < 3; ++i)
            __builtin_amdgcn_global_load_lds(
                (const AS1 void*)(src + i * 1024),
                (AS3 void*)&sA[buf][w * 1536 + i * 512],
                16, 0, 0);
    };
    auto stageB = [&](int buf, int u) {       // c-chunk u*8, wave w -> c=u*8+w
        const char* src = (const char*)(pool + ((size_t)(j * C_ + u * 8 + w) * NB + n0) * 12)
                        + lane * 16;
#pragma unroll
        for (int i = 0; i < 6; ++i)
            __builtin_amdgcn_global_load_lds(
                (const AS1 void*)(src + i * 1024),
                (AS3 void*)&sB[buf][w * 3072 + i * 512],
                16, 0, 0);
    };
    auto ldA = [&](int buf, int m, int ks) -> bf16x8 {
        int ch = (lane >> 4) ^ ((m >> 1) & 3);
        return *(const bf16x8*)&sA[buf][m * 96 + ks * 32 + ch * 8];
    };
    auto ldB = [&](int buf, int n, int ks) -> bf16x8 {
        int q0 = ks * 32 + (lane >> 4) * 8;
        int c1 = q0 / 12, a1 = q0 - c1 * 12;
        int q2 = q0 + 4;
        int c2 = q2 / 12, a2 = q2 - c2 * 12;
        bf16x4 lo = *(const bf16x4*)&sB[buf][c1 * 3072 + n * 12 + a1];
        bf16x4 hi = *(const bf16x4*)&sB[buf][c2 * 3072 + n * 12 + a2];
        return __builtin_shufflevector(lo, hi, 0, 1, 2, 3, 4, 5, 6, 7);
    };

    f32x4 acc[4][4];
#pragma unroll
    for (int i = 0; i < 4; ++i)
#pragma unroll
        for (int jj = 0; jj < 4; ++jj) acc[i][jj] = (f32x4){0.f, 0.f, 0.f, 0.f};

    const int NTL = 16;                  // tiles per group
    stageA(0, 0);
    stageB(0, 0);

    for (int u = 0; u < NTL; ++u) {
        int cur = u & 1;
        if (u + 1 < NTL) {
            stageA(cur ^ 1, u + 1);
            stageB(cur ^ 1, u + 1);
            VMW(9);
        } else {
            VMW(0);
        }
        barrier_();
#pragma unroll
        for (int ks = 0; ks < 3; ++ks) {
            bf16x8 af[4], bf_[4];
#pragma unroll
            for (int mf = 0; mf < 4; ++mf)
                af[mf] = ldA(cur, wm * 64 + mf * 16 + lq, ks);
#pragma unroll
            for (int nf = 0; nf < 4; ++nf)
                bf_[nf] = ldB(cur, wn * 64 + nf * 16 + lq, ks);
            lgkm0_();
            __builtin_amdgcn_s_setprio(1);
#pragma unroll
            for (int mf = 0; mf < 4; ++mf)
#pragma unroll
                for (int nf = 0; nf < 4; ++nf)
                    acc[mf][nf] = __builtin_amdgcn_mfma_f32_16x16x32_bf16(
                        af[mf], bf_[nf], acc[mf][nf], 0, 0, 0);
            __builtin_amdgcn_s_setprio(0);
        }
        barrier_();
    }

    u16* Cs = Ctb + (size_t)sp * (1536 * (size_t)NB);
#pragma unroll
    for (int mf = 0; mf < 4; ++mf)
#pragma unroll
        for (int nf = 0; nf < 4; ++nf) {
            int col = n0 + wn * 64 + nf * 16 + lq;
#pragma unroll
            for (int v = 0; v < 4; ++v) {
                int drow = wm * 64 + mf * 16 + ((lane >> 4) << 2) + v;
                Cs[(size_t)(r * 128 + drow) * NB + col] = f2bf(acc[mf][nf][v]);
            }
        }
}

// ---------------------------------------------------------------------------
// pass4c: out[b,d,p,r] = sum_{sp<5} Ct[(b*5+sp)][r*128+d][p]
// ---------------------------------------------------------------------------
__global__ __launch_bounds__(256) void pass4c(const u16* __restrict__ Ct,
                                              float* __restrict__ out) {
    __shared__ float lds[12 * 256];
    int bid = blockIdx.x;
    int pch = bid & 3;
    int d   = (bid >> 2) & 127;
    int b   = bid >> 9;
    int p0  = pch * 256;
    int t   = threadIdx.x;
#pragma unroll
    for (int r = 0; r < 12; ++r) {
        float s = 0.f;
#pragma unroll
        for (int sp = 0; sp < 5; ++sp) {
            size_t idx = ((size_t)(b * 5 + sp) * 1536 + (r * 128 + d)) * NB + p0 + t;
            s += bf2f(Ct[idx]);
        }
        lds[r * 256 + t] = s;
    }
    __syncthreads();
    float* obase = out + ((size_t)((b * D_ + d) * P_ + p0)) * 12;
#pragma unroll
    for (int q = 0; q < 3; ++q) {
        int e0 = q * 1024 + t * 4;
        float4 v;
        { int e = e0 + 0; int p = e / 12; int r = e - p * 12; v.x = lds[r * 256 + p]; }
        { int e = e0 + 1; int p = e / 12; int r = e - p * 12; v.y = lds[r * 256 + p]; }
        { int e = e0 + 2; int p = e / 12; int r = e - p * 12; v.z = lds[r * 256 + p]; }
        { int e = e0 + 3; int p = e / 12; int r = e - p * 12; v.w = lds[r * 256 + p]; }
        *(float4*)(obase + e0) = v;
    }
}

// ---------------------------------------------------------------------------
// fallback: direct naive computation (only if workspace is tiny)
// ---------------------------------------------------------------------------
__global__ __launch_bounds__(256) void naive_kernel(const float* __restrict__ x,
                                                    const float* __restrict__ W,
                                                    const int* __restrict__ kidx3,
                                                    const int* __restrict__ aidx3,
                                                    float* __restrict__ out) {
    long long t = (long long)blockIdx.x * 256 + threadIdx.x;
    if (t >= (long long)B_ * D_ * P_ * R_) return;
    int r = (int)(t % 12);
    int p = (int)((t / 12) % P_);
    int d = (int)((t / (12 * P_)) % D_);
    int b = (int)(t / (12 * (long long)P_ * D_));
    int kk[K_];
    int aa[A_];
#pragma unroll
    for (int k = 0; k < K_; ++k) kk[k] = kidx3[(k * 12 + 0) * 12 + r];
#pragma unroll
    for (int a = 0; a < A_; ++a) aa[a] = aidx3[(0 * 12 + a) * 12 + r];
    float sum = 0.f;
    for (int c = 0; c < C_; ++c) {
        const float* wrow = W + (size_t)(d * C_ + c) * 60;
        const float* xrow = x + ((size_t)(b * C_ + c) * K_) * (P_ * A_) + (size_t)p * A_;
        for (int k = 0; k < K_; ++k) {
            const float* wk = wrow + kk[k] * 12;
            const float* xk = xrow + (size_t)k * (P_ * A_);
#pragma unroll
            for (int a = 0; a < A_; ++a) sum += wk[aa[a]] * xk[a];
        }
    }
    out[t] = sum;
}

extern "C" void kernel_launch(void* const* d_in, const int* in_sizes, int n_in,
                              void* d_out, int out_size, void* d_ws, size_t ws_size,
                              hipStream_t stream) {
    const float* x     = (const float*)d_in[0];
    const float* W     = (const float*)d_in[1];
    const int*   kidx3 = (const int*)d_in[2];
    const int*   aidx3 = (const int*)d_in[3];
    float*       out   = (float*)d_out;

    const size_t POOLB = (size_t)26 * C_ * NB * 12 * 2;        //  81,788,928
    const size_t AB    = (size_t)12 * 80 * 128 * 96 * 2;       //  23,592,960
    const size_t CT5   = (size_t)B_ * 5 * 1536 * NB * 2;       //  62,914,560

    if (ws_size >= POOLB + AB + CT5) {
        u16* pool = (u16*)d_ws;
        u16* Abuf = (u16*)((char*)d_ws + POOLB);
        u16* Ct   = (u16*)((char*)d_ws + POOLB + AB);
        abuild<<<5760, 256, 0, stream>>>(W, aidx3, Abuf);
        for (int b = 0; b < 4; ++b) {
            const float* xb = x + (size_t)b * C_ * K_ * P_ * A_;
            u16* Ctb = Ct + (size_t)b * 5 * 1536 * NB;
            poolk_b<<<dim3(128, 4), 512, 0, stream>>>(xb, kidx3, pool);
            gemmSb<<<240, 512, 0, stream>>>(Abuf, pool, kidx3, Ctb);
        }
        pass4c<<<2048, 256, 0, stream>>>(Ct, out);
    } else {
        naive_kernel<<<(B_ * D_ * P_ * R_) / 256, 256, 0, stream>>>(x, W, kidx3, aidx3, out);
    }
}

// Round 9
// 364.166 us; speedup vs baseline: 1.0781x; 1.0781x over previous
//
#include <hip/hip_runtime.h>
#include <hip/hip_bf16.h>

typedef __bf16 bf16x8 __attribute__((ext_vector_type(8)));
typedef __bf16 bf16x4 __attribute__((ext_vector_type(4)));
typedef float f32x4 __attribute__((ext_vector_type(4)));
typedef float f32x3 __attribute__((ext_vector_type(3)));
typedef unsigned int u32x3 __attribute__((ext_vector_type(3)));
typedef unsigned short u16;
typedef unsigned int u32;

// Problem constants
#define B_   4
#define C_   128
#define K_   13
#define A_   12
#define P_   1024
#define D_   128
#define R_   12
#define MT   1536
#define NT   4096
// K' = 5 groups * 128c * 12a = 7680 = 80 tiles of 96
#define KP   7680

#define AS1 __attribute__((address_space(1)))
#define AS3 __attribute__((address_space(3)))

__device__ __forceinline__ u16 f2bf(float f) {
    u32 u = __builtin_bit_cast(u32, f);
    u32 r = (u + 0x7FFFu + ((u >> 16) & 1u)) >> 16;
    return (u16)r;
}
__device__ __forceinline__ float bf2f(u16 v) {
    u32 u = (u32)v << 16;
    return __builtin_bit_cast(float, u);
}
__device__ __forceinline__ u32 pack2(float lo, float hi) {
    return (u32)f2bf(lo) | ((u32)f2bf(hi) << 16);
}

__device__ __forceinline__ void barrier_() {
    asm volatile("" ::: "memory");
    __builtin_amdgcn_s_barrier();
    asm volatile("" ::: "memory");
}
__device__ __forceinline__ void lgkm0_() {
    asm volatile("s_waitcnt lgkmcnt(0)" ::: "memory");
    __builtin_amdgcn_sched_barrier(0);
}
#define VMW(n) asm volatile("s_waitcnt vmcnt(" #n ")" ::: "memory")

// ---------------------------------------------------------------------------
// poolk: x[b,c,k,p,a] f32 -> pool[j][c][n=b*1024+p][a] bf16, j in [0,26):
//   j=0..12 : raw k-slices;  j=13 : T = sum_{k<12} x;  j=14+r : N_r = shell1 sum
// ---------------------------------------------------------------------------
__global__ __launch_bounds__(512) void poolk(const float* __restrict__ x,
                                             const int* __restrict__ kidx3,
                                             u16* __restrict__ pool) {
    const int c = blockIdx.x;
    const int b = blockIdx.y;
    const int t = threadIdx.x;
    const int ah = t & 1, aoff = ah * 6;

    u32 m1[12];
#pragma unroll
    for (int k = 0; k < 12; ++k) {
        u32 m = 0;
#pragma unroll
        for (int r = 0; r < 12; ++r)
            m |= (kidx3[k * 144 + r] == 1 ? 1u : 0u) << r;
        m1[k] = m;
    }

    const float* xb = x + (size_t)(b * C_ + c) * (K_ * (size_t)P_ * A_);
    const size_t cslab = ((size_t)c * 4096) * 12;
    const size_t jstride = (size_t)C_ * 4096 * 12;

    for (int pp = 0; pp < 4; ++pp) {
        int p = pp * 256 + (t >> 1);
        int n = b * P_ + p;
        size_t obase = cslab + (size_t)n * 12 + aoff;
        float T[6] = {0.f, 0.f, 0.f, 0.f, 0.f, 0.f};
        float N[12][6];
#pragma unroll
        for (int r = 0; r < 12; ++r)
#pragma unroll
            for (int j = 0; j < 6; ++j) N[r][j] = 0.f;

#pragma unroll
        for (int k = 0; k < 13; ++k) {
            const float* s = xb + (size_t)k * (P_ * A_) + p * 12 + aoff;
            f32x3 v0 = *(const f32x3*)s;
            f32x3 v1 = *(const f32x3*)(s + 3);
            float v[6] = {v0.x, v0.y, v0.z, v1.x, v1.y, v1.z};
            u32x3 o;
            o.x = pack2(v[0], v[1]); o.y = pack2(v[2], v[3]); o.z = pack2(v[4], v[5]);
            *(u32x3*)(pool + (size_t)k * jstride + obase) = o;
            if (k < 12) {
#pragma unroll
                for (int j = 0; j < 6; ++j) T[j] += v[j];
                u32 m = m1[k];
#pragma unroll
                for (int r = 0; r < 12; ++r) {
                    if (m & (1u << r)) {
#pragma unroll
                        for (int j = 0; j < 6; ++j) N[r][j] += v[j];
                    }
                }
            }
        }
        {
            u32x3 o;
            o.x = pack2(T[0], T[1]); o.y = pack2(T[2], T[3]); o.z = pack2(T[4], T[5]);
            *(u32x3*)(pool + (size_t)13 * jstride + obase) = o;
        }
#pragma unroll
        for (int r = 0; r < 12; ++r) {
            u32x3 o;
            o.x = pack2(N[r][0], N[r][1]); o.y = pack2(N[r][2], N[r][3]); o.z = pack2(N[r][4], N[r][5]);
            *(u32x3*)(pool + (size_t)(14 + r) * jstride + obase) = o;
        }
    }
}

// ---------------------------------------------------------------------------
// abuild: tile-major panels Ab[r][tile][d][96] bf16 (each (r,tile) panel is a
// contiguous 24576-B byte-image of the LDS A-tile, XOR swizzle baked in:
// phys chunk chp holds logical chunk chp ^ ((d>>1)&3) within each ks-group).
// Values: g0:(W0-W2) g1:(W1-W2) g2:W2 g3:(W3-W2) g4:W4 at aa = aidx[a,r],
// logical col q = g*1536 + c*12 + a.
// ---------------------------------------------------------------------------
__global__ __launch_bounds__(256) void abuild(const float* __restrict__ W,
                                              const int* __restrict__ aidx3,
                                              u16* __restrict__ Ab) {
    int gidx = blockIdx.x * 256 + threadIdx.x;   // 12*128*960 = 1,474,560
    int r   = gidx / (128 * 960);
    int rem = gidx - r * (128 * 960);
    int d   = rem / 960;
    int p8  = rem - d * 960;
    int phys = p8 * 8;
    int tile = phys / 96;
    int w96  = phys - tile * 96;
    int ks   = w96 >> 5;
    int chp  = (w96 >> 3) & 3;
    int ch   = chp ^ ((d >> 1) & 3);
    int qbase = tile * 96 + ks * 32 + ch * 8;
    u16 o[8];
#pragma unroll
    for (int e = 0; e < 8; ++e) {
        int q  = qbase + e;
        int g  = q / 1536;
        int qq = q - g * 1536;
        int c  = qq / 12;
        int a  = qq - c * 12;
        int aa = aidx3[a * 12 + r];
        const float* wb = W + ((size_t)(d * C_ + c) * 5) * 12 + aa;
        float val;
        if (g == 2)      val = wb[2 * 12];
        else if (g == 4) val = wb[4 * 12];
        else             val = wb[g * 12] - wb[2 * 12];
        o[e] = f2bf(val);
    }
    uint4 v;
    v.x = (u32)o[0] | ((u32)o[1] << 16);
    v.y = (u32)o[2] | ((u32)o[3] << 16);
    v.z = (u32)o[4] | ((u32)o[5] << 16);
    v.w = (u32)o[6] | ((u32)o[7] << 16);
    *(uint4*)(Ab + (((size_t)(r * 80 + tile) * 128 + d) * 96 + w96)) = v;
}

// ---------------------------------------------------------------------------
// gemmS: per r: C_r[d][n] = sum_{q<7680} Ab_r[d][q] * B_r[n][q]
// BM=128 (all d), BN=256, BK=96, 8 waves (2Mx4N), dbuf LDS, 16B staging only.
// Split-K x4 -> bf16 partial slabs (pass4b reduces). 768 blocks = 3 rounds.
// ---------------------------------------------------------------------------
__global__ __launch_bounds__(512) void gemmS(const u16* __restrict__ Ab,
                                             const u16* __restrict__ pool,
                                             const int* __restrict__ kidx3,
                                             u16* __restrict__ C) {
    __shared__ __align__(16) u16 sA[2][128 * 96];
    __shared__ __align__(16) u16 sB[2][8 * 256 * 12];

    int bx = blockIdx.x;                 // 768 = 16nt * 12r * 4sp
    int nt = bx & 15;
    int r  = (bx >> 4) % 12;
    int sp = bx / 192;
    int n0 = nt * 256;

    int k0r = 0, k3r = 0;
    for (int k = 0; k < 13; ++k) {
        int kv = kidx3[k * 144 + r];
        if (kv == 0) k0r = k;
        if (kv == 3) k3r = k;
    }

    int lane = threadIdx.x & 63;
    int w    = threadIdx.x >> 6;
    int wm   = w >> 2, wn = w & 3;
    int lq   = lane & 15;

    auto stageA = [&](int buf, int tile) {
        const char* src = (const char*)(Ab + (size_t)(r * 80 + tile) * (128 * 96))
                        + w * 3072 + lane * 16;
#pragma unroll
        for (int i = 0; i < 3; ++i)
            __builtin_amdgcn_global_load_lds(
                (const AS1 void*)(src + i * 1024),
                (AS3 void*)&sA[buf][w * 1536 + i * 512],
                16, 0, 0);
    };
    auto stageB = [&](int buf, int tile) {
        int gt = tile >> 4;
        int c  = ((tile & 15) << 3) + w;
        int j  = (gt == 0) ? k0r : (gt == 1) ? (14 + r) : (gt == 2) ? 13
               : (gt == 3) ? k3r : 12;
        const char* src = (const char*)(pool + ((size_t)(j * C_ + c) * 4096 + n0) * 12)
                        + lane * 16;
#pragma unroll
        for (int i = 0; i < 6; ++i)
            __builtin_amdgcn_global_load_lds(
                (const AS1 void*)(src + i * 1024),
                (AS3 void*)&sB[buf][w * 3072 + i * 512],
                16, 0, 0);
    };
    auto ldA = [&](int buf, int m, int ks) -> bf16x8 {
        int ch = (lane >> 4) ^ ((m >> 1) & 3);
        return *(const bf16x8*)&sA[buf][m * 96 + ks * 32 + ch * 8];
    };
    auto ldB = [&](int buf, int n, int ks) -> bf16x8 {
        int q0 = ks * 32 + (lane >> 4) * 8;
        int c1 = q0 / 12, a1 = q0 - c1 * 12;
        int q2 = q0 + 4;
        int c2 = q2 / 12, a2 = q2 - c2 * 12;
        bf16x4 lo = *(const bf16x4*)&sB[buf][c1 * 3072 + n * 12 + a1];
        bf16x4 hi = *(const bf16x4*)&sB[buf][c2 * 3072 + n * 12 + a2];
        return __builtin_shufflevector(lo, hi, 0, 1, 2, 3, 4, 5, 6, 7);
    };

    f32x4 acc[4][4];
#pragma unroll
    for (int i = 0; i < 4; ++i)
#pragma unroll
        for (int j = 0; j < 4; ++j) acc[i][j] = (f32x4){0.f, 0.f, 0.f, 0.f};

    const int NTL2 = 20;               // 80 K-tiles / 4 splits
    int t0 = sp * NTL2;

    stageA(0, t0);
    stageB(0, t0);

    for (int u = 0; u < NTL2; ++u) {
        int cur = u & 1;
        if (u + 1 < NTL2) {
            stageA(cur ^ 1, t0 + u + 1);
            stageB(cur ^ 1, t0 + u + 1);
            VMW(9);
        } else {
            VMW(0);
        }
        barrier_();
#pragma unroll
        for (int ks = 0; ks < 3; ++ks) {
            bf16x8 af[4], bf_[4];
#pragma unroll
            for (int mf = 0; mf < 4; ++mf)
                af[mf] = ldA(cur, wm * 64 + mf * 16 + lq, ks);
#pragma unroll
            for (int nf = 0; nf < 4; ++nf)
                bf_[nf] = ldB(cur, wn * 64 + nf * 16 + lq, ks);
            lgkm0_();
            __builtin_amdgcn_s_setprio(1);
#pragma unroll
            for (int mf = 0; mf < 4; ++mf)
#pragma unroll
                for (int nf = 0; nf < 4; ++nf)
                    acc[mf][nf] = __builtin_amdgcn_mfma_f32_16x16x32_bf16(
                        af[mf], bf_[nf], acc[mf][nf], 0, 0, 0);
            __builtin_amdgcn_s_setprio(0);
        }
        barrier_();
    }

    u16* Cs = C + (size_t)sp * ((size_t)MT * NT);
#pragma unroll
    for (int mf = 0; mf < 4; ++mf)
#pragma unroll
        for (int nf = 0; nf < 4; ++nf) {
            int col = n0 + wn * 64 + nf * 16 + lq;
#pragma unroll
            for (int v = 0; v < 4; ++v) {
                int drow = wm * 64 + mf * 16 + ((lane >> 4) << 2) + v;
                Cs[(size_t)(r * 128 + drow) * NT + col] = f2bf(acc[mf][nf][v]);
            }
        }
}

// ---------------------------------------------------------------------------
// pass4b: out[b,d,p,r] = sum_s Ct[s][r*128 + d][b*1024 + p]
// ---------------------------------------------------------------------------
template <int SPLIT>
__global__ __launch_bounds__(256) void pass4b(const u16* __restrict__ Ct,
                                              float* __restrict__ out) {
    __shared__ float lds[12 * 256];
    int bid = blockIdx.x;
    int pch = bid & 3;
    int d   = (bid >> 2) & 127;
    int b   = bid >> 9;
    int p0  = pch * 256;
    int t   = threadIdx.x;
#pragma unroll
    for (int r = 0; r < 12; ++r) {
        size_t off = (size_t)(r * D_ + d) * NT + b * P_ + p0 + t;
        float s = 0.f;
#pragma unroll
        for (int sp = 0; sp < SPLIT; ++sp)
            s += bf2f(Ct[(size_t)sp * MT * NT + off]);
        lds[r * 256 + t] = s;
    }
    __syncthreads();
    float* obase = out + ((size_t)((b * D_ + d) * P_ + p0)) * 12;
#pragma unroll
    for (int q = 0; q < 3; ++q) {
        int e0 = q * 1024 + t * 4;
        float4 v;
        { int e = e0 + 0; int p = e / 12; int r = e - p * 12; v.x = lds[r * 256 + p]; }
        { int e = e0 + 1; int p = e / 12; int r = e - p * 12; v.y = lds[r * 256 + p]; }
        { int e = e0 + 2; int p = e / 12; int r = e - p * 12; v.z = lds[r * 256 + p]; }
        { int e = e0 + 3; int p = e / 12; int r = e - p * 12; v.w = lds[r * 256 + p]; }
        *(float4*)(obase + e0) = v;
    }
}

// ---------------------------------------------------------------------------
// fallback: direct naive computation (only if workspace is tiny)
// ---------------------------------------------------------------------------
__global__ __launch_bounds__(256) void naive_kernel(const float* __restrict__ x,
                                                    const float* __restrict__ W,
                                                    const int* __restrict__ kidx3,
                                                    const int* __restrict__ aidx3,
                                                    float* __restrict__ out) {
    long long t = (long long)blockIdx.x * 256 + threadIdx.x;
    if (t >= (long long)B_ * D_ * P_ * R_) return;
    int r = (int)(t % 12);
    int p = (int)((t / 12) % P_);
    int d = (int)((t / (12 * P_)) % D_);
    int b = (int)(t / (12 * (long long)P_ * D_));
    int kk[K_];
    int aa[A_];
#pragma unroll
    for (int k = 0; k < K_; ++k) kk[k] = kidx3[(k * 12 + 0) * 12 + r];
#pragma unroll
    for (int a = 0; a < A_; ++a) aa[a] = aidx3[(0 * 12 + a) * 12 + r];
    float sum = 0.f;
    for (int c = 0; c < C_; ++c) {
        const float* wrow = W + (size_t)(d * C_ + c) * 60;
        const float* xrow = x + ((size_t)(b * C_ + c) * K_) * (P_ * A_) + (size_t)p * A_;
        for (int k = 0; k < K_; ++k) {
            const float* wk = wrow + kk[k] * 12;
            const float* xk = xrow + (size_t)k * (P_ * A_);
#pragma unroll
            for (int a = 0; a < A_; ++a) sum += wk[aa[a]] * xk[a];
        }
    }
    out[t] = sum;
}

extern "C" void kernel_launch(void* const* d_in, const int* in_sizes, int n_in,
                              void* d_out, int out_size, void* d_ws, size_t ws_size,
                              hipStream_t stream) {
    const float* x     = (const float*)d_in[0];
    const float* W     = (const float*)d_in[1];
    const int*   kidx3 = (const int*)d_in[2];
    const int*   aidx3 = (const int*)d_in[3];
    float*       out   = (float*)d_out;

    const size_t POOL = (size_t)26 * C_ * 4096 * 12 * 2;  // 327,155,712
    const size_t AB   = (size_t)12 * 80 * 128 * 96 * 2;   //  23,592,960
    const size_t CTH  = (size_t)MT * NT * 2;              //  12,582,912 per slab

    if (ws_size >= POOL + AB + 4 * CTH) {
        u16* pool = (u16*)d_ws;
        u16* Abuf = (u16*)((char*)d_ws + POOL);
        u16* Ct   = (u16*)((char*)d_ws + POOL + AB);
        poolk<<<dim3(128, 4), 512, 0, stream>>>(x, kidx3, pool);
        abuild<<<5760, 256, 0, stream>>>(W, aidx3, Abuf);
        gemmS<<<768, 512, 0, stream>>>(Abuf, pool, kidx3, Ct);
        pass4b<4><<<2048, 256, 0, stream>>>(Ct, out);
    } else {
        naive_kernel<<<(B_ * D_ * P_ * R_) / 256, 256, 0, stream>>>(x, W, kidx3, aidx3, out);
    }
}